// Round 9
// baseline (301.283 us; speedup 1.0000x reference)
//
#include <hip/hip_runtime.h>
#include <hip/hip_bf16.h>
#include <math.h>

#define B_   16
#define S_   4096
#define DIN  1024
#define V_   512
#define FOUT 120

typedef __attribute__((ext_vector_type(8))) short bf16x8;
typedef __attribute__((ext_vector_type(4))) float f32x4;

#define AS1 __attribute__((address_space(1)))
#define AS3 __attribute__((address_space(3)))

__device__ const float CSCALE = 0.1f / (64.0f * 4096.0f);
__device__ const float EPSF = 1e-5f;

__device__ inline void gl2lds16(const void* g, void* l) {
  __builtin_amdgcn_global_load_lds((const AS1 unsigned int*)g,
                                   (AS3 unsigned int*)l, 16, 0, 0);
}

// fp32 -> bf16 RNE
__device__ inline unsigned short f2b(float f) {
  unsigned u = __builtin_bit_cast(unsigned, f);
  unsigned r = (u + 0x7FFFu + ((u >> 16) & 1u)) >> 16;
  return (unsigned short)r;
}

__device__ inline bf16x8 pack8(float4 a, float4 b) {
  bf16x8 r;
  r[0] = (short)f2b(a.x); r[1] = (short)f2b(a.y);
  r[2] = (short)f2b(a.z); r[3] = (short)f2b(a.w);
  r[4] = (short)f2b(b.x); r[5] = (short)f2b(b.y);
  r[6] = (short)f2b(b.z); r[7] = (short)f2b(b.w);
  return r;
}

// Wt frag-major (r7/r8-verified): e = ((ct*32 + k)*24 + f)*64 + l ; f = 3*nf + g
// lane l: channel ct*128 + nf*16 + (l&15), k-elem k*32 + (l>>4)*8
__global__ void msr_convw(const float* __restrict__ Wq, const float* __restrict__ Wk,
                          const float* __restrict__ Wv, unsigned short* __restrict__ Wt) {
  int e = blockIdx.x * 256 + threadIdx.x;
  int l = e & 63;
  int f = (e >> 6) % 24;
  int ck = (e >> 6) / 24;
  int k = ck & 31;
  int ct = ck >> 5;
  int nf = f / 3, g = f % 3;
  const float* W = (g == 0) ? Wq : (g == 1) ? Wk : Wv;
  int ch = ct * 128 + nf * 16 + (l & 15);
  const float* src = W + (size_t)ch * DIN + k * 32 + (l >> 4) * 8;
  float4 a = *(const float4*)src;
  float4 b = *(const float4*)(src + 4);
  *(bf16x8*)(Wt + (size_t)e * 8) = pack8(a, b);
}

// Xb = bf16(x), row-major [65536][1024] (r6-r8-verified)
__global__ __launch_bounds__(256) void msr_convx(const float* __restrict__ x,
                                                 unsigned short* __restrict__ Xb) {
  const size_t stride = (size_t)gridDim.x * 256;
  for (size_t i = blockIdx.x * 256ull + threadIdx.x; i < 8388608ull; i += stride) {
    const float* src = x + i * 8;
    float4 a = *(const float4*)src;
    float4 b = *(const float4*)(src + 4);
    *(bf16x8*)(Xb + i * 8) = pack8(a, b);
  }
}

#define WAITVM7  asm volatile("s_waitcnt vmcnt(7)" ::: "memory")
#define WAITVM0  asm volatile("s_waitcnt vmcnt(0)" ::: "memory")
#define WAITLGKM asm volatile("s_waitcnt lgkmcnt(0)" ::: "memory")
#define SCHEDB   __builtin_amdgcn_sched_barrier(0)
#define BARRIER  { asm volatile("" ::: "memory"); __builtin_amdgcn_s_barrier(); asm volatile("" ::: "memory"); }

// Main: 256 thr = 4 waves -> TWO blocks/CU (independent barrier domains).
// Block tile: M=64 x 128ch x 3g, BK=32, 32 steps. Wave tile 64r x 32ch x 3g (acc 96).
// LDS 81920 B exactly: A 2x4KB (reg-staged, T14) + B 3x24KB (gl2lds, wave-local).
// One barrier/step; single counted vmcnt(7) (6 B-gl2lds + 1 A-load per wave per step).
template <bool DIRECT>
__global__ __launch_bounds__(256, 2) void msr_main(
    const float* __restrict__ x, const unsigned short* __restrict__ Xb,
    const unsigned short* __restrict__ Wt, float* __restrict__ outacc) {
  const int bid = blockIdx.x;
  const int xcd = bid & 7;
  const int j = bid >> 3;                 // 0..511 (per-XCD dispatch order)
  const int ct = j & 3;                   // 4 consecutive same-XCD blocks share rt
  const int rt = xcd * 128 + (j >> 2);    // 0..1023, bijective
  const int r0 = rt << 6;

  __shared__ __align__(16) unsigned char smem_[81920];  // A 2x4KB | B 3x24KB

  const int t = threadIdx.x;
  const int w = t >> 6, lane = t & 63;
  const int w6 = w * 6;
  const int l16 = lane * 16;

  // B source: wave w stages/consumes exactly frags f = w6..w6+5 (wave-local)
  const unsigned short* pWt =
      Wt + (((size_t)ct * 32) * 24 + w6) * 512 + (size_t)lane * 8;
  // A source: thread t -> row t>>2 (0..63), k-octet t&3 (r8-verified mapping)
  const unsigned short* pXa = Xb + (size_t)(r0 + (t >> 2)) * DIN + (t & 3) * 8;
  const float* pXf = x + (size_t)(r0 + (t >> 2)) * DIN + (t & 3) * 8;
  const int awoff = (((t >> 2) >> 4) * 64 + (t & 3) * 16 + ((t >> 2) & 15)) * 16;

  f32x4 acc[3][4][2];
#pragma unroll
  for (int g = 0; g < 3; ++g)
#pragma unroll
    for (int m = 0; m < 4; ++m)
#pragma unroll
      for (int n = 0; n < 2; ++n) acc[g][m][n] = (f32x4){0.f, 0.f, 0.f, 0.f};

  bf16x8 afr[4], bfr0[3], bfr1[3];
  bf16x8 xE, xO;

#define ALOAD(REG, PX, PXF, C2) { \
  if constexpr (DIRECT) { \
    const unsigned short* _p = (PX) + (size_t)(C2) * 32; \
    asm volatile("global_load_dwordx4 %0, %1, off" : "=v"(REG) : "v"(_p) : "memory"); \
  } else { \
    const float* _pf = (PXF) + (size_t)(C2) * 32; \
    REG = pack8(*(const float4*)_pf, *(const float4*)(_pf + 4)); \
  } }

#define STAGEB(PW, C2, SB) { \
  _Pragma("unroll") for (int i = 0; i < 6; ++i) \
    gl2lds16((PW) + (size_t)(C2) * 12288 + i * 512, \
             smem_ + 8192 + (SB) * 24576 + (w6 + i) * 1024); }

#define READS(KB, AB) { \
  _Pragma("unroll") for (int m = 0; m < 4; ++m) \
    afr[m] = *(const bf16x8*)(smem_ + (AB) * 4096 + (m * 64 + lane) * 16); \
  _Pragma("unroll") for (int g = 0; g < 3; ++g) \
    bfr0[g] = *(const bf16x8*)(smem_ + 8192 + (KB) * 24576 + (w6 + g) * 1024 + l16); \
  _Pragma("unroll") for (int g = 0; g < 3; ++g) \
    bfr1[g] = *(const bf16x8*)(smem_ + 8192 + (KB) * 24576 + (w6 + 3 + g) * 1024 + l16); }

#define MFMAP { \
  __builtin_amdgcn_s_setprio(1); \
  _Pragma("unroll") for (int g = 0; g < 3; ++g) \
  _Pragma("unroll") for (int m = 0; m < 4; ++m) { \
    acc[g][m][0] = __builtin_amdgcn_mfma_f32_16x16x32_bf16(afr[m], bfr0[g], acc[g][m][0], 0, 0, 0); \
    acc[g][m][1] = __builtin_amdgcn_mfma_f32_16x16x32_bf16(afr[m], bfr1[g], acc[g][m][1], 0, 0, 0); \
  } \
  __builtin_amdgcn_s_setprio(0); }

#define STEP(KB, AB, SB, C2, REGW, REGL) { \
  READS(KB, AB); \
  STAGEB(pWi, C2, SB); \
  ALOAD(REGL, pXi, pXfi, C2); \
  SCHEDB; \
  MFMAP; \
  WAITVM7; \
  *(bf16x8*)(smem_ + ((AB) ^ 1) * 4096 + awoff) = REGW; \
  WAITLGKM; \
  BARRIER; }

  // ---- prologue: A(0),A(1) to regs; B(0),B(1) staged; A(0) written ----
  ALOAD(xE, pXa, pXf, 0);
  STAGEB(pWt, 0, 0);
  STAGEB(pWt, 1, 1);
  ALOAD(xO, pXa, pXf, 1);
  if constexpr (DIRECT) { asm volatile("s_waitcnt vmcnt(13)" ::: "memory"); }
  *(bf16x8*)(smem_ + awoff) = xE;        // A(0) -> Abuf0
  WAITVM7;                               // B(0) landed (B(1)x6 + xO in flight)
  WAITLGKM;
  BARRIER;

  // ---- steps 0..29: 5 iterations x 6 steps (LCM of 2 A-bufs, 3 B-bufs) ----
  const unsigned short* pWi = pWt;
  const unsigned short* pXi = pXa;
  const float* pXfi = pXf;
#pragma unroll 1
  for (int i = 0; i < 5; ++i) {
    STEP(0, 0, 2, 2, xO, xE);
    STEP(1, 1, 0, 3, xE, xO);
    STEP(2, 0, 1, 4, xO, xE);
    STEP(0, 1, 2, 5, xE, xO);
    STEP(1, 0, 0, 6, xO, xE);
    STEP(2, 1, 1, 7, xE, xO);
    pWi += 6 * 12288;
    pXi += 6 * 32;
    pXfi += 6 * 32;
  }
  // ---- step 30 (KB=0, AB=0): no stage; drain; write A(31) ----
  READS(0, 0);
  SCHEDB;
  MFMAP;
  WAITVM0;
  *(bf16x8*)(smem_ + 4096 + awoff) = xO;   // A(31) -> Abuf1
  WAITLGKM;
  BARRIER;
  // ---- step 31 (KB=1, AB=1): compute only ----
  READS(1, 1);
  MFMAP;
#undef STEP
#undef MFMAP
#undef READS
#undef STAGEB
#undef ALOAD

  // ---- epilogue (r5-r8-verified): p = (q*k)[c^1]*v[c]; fold rows; atomicAdd ----
  float pd0 = 0.f, pd1 = 0.f;
#pragma unroll
  for (int m = 0; m < 4; ++m)
#pragma unroll
    for (int r = 0; r < 4; ++r) {
      float qk0 = acc[0][m][0][r] * acc[1][m][0][r];
      float qk1 = acc[0][m][1][r] * acc[1][m][1][r];
      pd0 += __shfl_xor(qk0, 1, 64) * acc[2][m][0][r];
      pd1 += __shfl_xor(qk1, 1, 64) * acc[2][m][1][r];
    }
  pd0 += __shfl_xor(pd0, 16, 64); pd0 += __shfl_xor(pd0, 32, 64);
  pd1 += __shfl_xor(pd1, 16, 64); pd1 += __shfl_xor(pd1, 32, 64);

  // d = (ct*128 + w*32 + n*16 + (lane&15)) % 64 ; h-block = r0>>9 = rt>>3
  if (lane < 16) {
    float* dst = &outacc[((rt >> 3) << 6) + (w & 1) * 32 + lane];
    atomicAdd(dst, pd0);
    atomicAdd(dst + 16, pd1);
  }
}

// Finish: per-batch RMSNorm -> exact gelu -> @ Wout.T (verified r1-r8)
__global__ __launch_bounds__(256) void msr_finish(
    const float* __restrict__ outacc, const float* __restrict__ gamma,
    const float* __restrict__ Wout, float* __restrict__ y) {
  const int b = blockIdx.x;
  const int t = threadIdx.x;
  __shared__ float g[V_];
  __shared__ float wsum[4];

  float v0 = outacc[b * V_ + t] * CSCALE;
  float v1 = outacc[b * V_ + 256 + t] * CSCALE;
  float ss = v0 * v0 + v1 * v1;
#pragma unroll
  for (int o = 32; o > 0; o >>= 1) ss += __shfl_down(ss, o, 64);
  if ((t & 63) == 0) wsum[t >> 6] = ss;
  __syncthreads();
  float tot = wsum[0] + wsum[1] + wsum[2] + wsum[3];
  float rs = rsqrtf(tot * (1.0f / (float)V_) + EPSF);

  float r0v = v0 * rs * gamma[t];
  float r1v = v1 * rs * gamma[t + 256];
  g[t]       = 0.5f * r0v * (1.0f + erff(r0v * 0.70710678118654752f));
  g[t + 256] = 0.5f * r1v * (1.0f + erff(r1v * 0.70710678118654752f));
  __syncthreads();

  if (t < FOUT) {
    const float* wr = Wout + (size_t)t * V_;
    float acc = 0.f;
#pragma unroll 4
    for (int c = 0; c < V_; c += 4) {
      float4 w4 = *(const float4*)(wr + c);
      acc += g[c] * w4.x + g[c + 1] * w4.y + g[c + 2] * w4.z + g[c + 3] * w4.w;
    }
    y[b * FOUT + t] = acc;
  }
}

extern "C" void kernel_launch(void* const* d_in, const int* in_sizes, int n_in,
                              void* d_out, int out_size, void* d_ws, size_t ws_size,
                              hipStream_t stream) {
  const float* x     = (const float*)d_in[0];
  const float* Wq    = (const float*)d_in[1];
  const float* Wk    = (const float*)d_in[2];
  const float* Wv    = (const float*)d_in[3];
  const float* Wout  = (const float*)d_in[4];
  const float* gamma = (const float*)d_in[5];

  float* outacc = (float*)d_ws;                                    // 32 KB
  unsigned short* Wt = (unsigned short*)((char*)d_ws + 32768);     // 3 MB
  unsigned short* Xb = (unsigned short*)((char*)d_ws + 32768 + 3145728);  // 128 MB
  float* y = (float*)d_out;

  const size_t need = 32768ull + 3145728ull + 134217728ull;

  msr_convw<<<768, 256, 0, stream>>>(Wq, Wk, Wv, Wt);
  hipMemsetAsync(outacc, 0, B_ * V_ * sizeof(float), stream);

  if (ws_size >= need) {
    msr_convx<<<2048, 256, 0, stream>>>(x, Xb);
    msr_main<true><<<4096, 256, 0, stream>>>(x, Xb, Wt, outacc);
  } else {
    msr_main<false><<<4096, 256, 0, stream>>>(x, Xb, Wt, outacc);
  }
  msr_finish<<<B_, 256, 0, stream>>>(outacc, gamma, Wout, y);
}

// Round 10
// 250.135 us; speedup vs baseline: 1.2045x; 1.2045x over previous
//
#include <hip/hip_runtime.h>
#include <hip/hip_bf16.h>
#include <math.h>

#define B_   16
#define S_   4096
#define DIN  1024
#define V_   512
#define FOUT 120

typedef __attribute__((ext_vector_type(8))) short bf16x8;
typedef __attribute__((ext_vector_type(4))) float f32x4;

__device__ const float CSCALE = 0.1f / (64.0f * 4096.0f);
__device__ const float EPSF = 1e-5f;

// fp32 -> bf16 RNE
__device__ inline unsigned short f2b(float f) {
  unsigned u = __builtin_bit_cast(unsigned, f);
  unsigned r = (u + 0x7FFFu + ((u >> 16) & 1u)) >> 16;
  return (unsigned short)r;
}

__device__ inline bf16x8 pack8(float4 a, float4 b) {
  bf16x8 r;
  r[0] = (short)f2b(a.x); r[1] = (short)f2b(a.y);
  r[2] = (short)f2b(a.z); r[3] = (short)f2b(a.w);
  r[4] = (short)f2b(b.x); r[5] = (short)f2b(b.y);
  r[6] = (short)f2b(b.z); r[7] = (short)f2b(b.w);
  return r;
}

// Wt frag-major (r7-r9-verified): e = ((ct*32 + k)*24 + f)*64 + l ; f = 3*nf + g
// lane l: channel ct*128 + nf*16 + (l&15), k-elem k*32 + (l>>4)*8
__global__ void msr_convw(const float* __restrict__ Wq, const float* __restrict__ Wk,
                          const float* __restrict__ Wv, unsigned short* __restrict__ Wt) {
  int e = blockIdx.x * 256 + threadIdx.x;
  int l = e & 63;
  int f = (e >> 6) % 24;
  int ck = (e >> 6) / 24;
  int k = ck & 31;
  int ct = ck >> 5;
  int nf = f / 3, g = f % 3;
  const float* W = (g == 0) ? Wq : (g == 1) ? Wk : Wv;
  int ch = ct * 128 + nf * 16 + (l & 15);
  const float* src = W + (size_t)ch * DIN + k * 32 + (l >> 4) * 8;
  float4 a = *(const float4*)src;
  float4 b = *(const float4*)(src + 4);
  *(bf16x8*)(Wt + (size_t)e * 8) = pack8(a, b);
}

#define WAITLGKM asm volatile("s_waitcnt lgkmcnt(0)" ::: "memory")
#define BARRIER  { asm volatile("" ::: "memory"); __builtin_amdgcn_s_barrier(); asm volatile("" ::: "memory"); }

// Main: 256 thr = 4 waves -> 2 blocks/CU (two independent barrier domains).
// Block tile M=64 x 128ch x 3g, BK=32, 32 steps. Wave tile 64r x 32ch x 3g (acc 96).
// B: wave-local, direct global->reg (bf16 Wt, L2/L3-resident), 1-step prefetch.
// A: x f32 coalesced -> pack8 -> ds_write dbuf 2x4KB (LDS carries ONLY A).
// One lgkm-only barrier per step; NO manual vmcnt (compiler-counted waits).
__global__ __launch_bounds__(256, 2) void msr_main(
    const float* __restrict__ x, const unsigned short* __restrict__ Wt,
    float* __restrict__ outacc) {
  const int bid = blockIdx.x;
  const int xcd = bid & 7;
  const int j = bid >> 3;               // 0..511 (per-XCD dispatch order)
  const int ct = j & 3;                 // 4 consecutive same-XCD blocks share rt
  const int rt = xcd * 128 + (j >> 2);  // 0..1023, bijective (r9-verified, FETCH~1x)
  const int r0 = rt << 6;

  __shared__ __align__(16) unsigned char smem_[8192];   // A dbuf 2x4KB

  const int t = threadIdx.x;
  const int w = t >> 6, lane = t & 63;
  const int w6 = w * 6;

  // B: wave w owns frags f = w6..w6+5; step k at pB + k*12288 shorts (r9 layout)
  const unsigned short* pB =
      Wt + (((size_t)ct * 32) * 24 + w6) * 512 + (size_t)lane * 8;

  // A loader: thread t -> row t>>2 (0..63), k-octet t&3 (coalesced 128B/4thr)
  const float* pX = x + (size_t)(r0 + (t >> 2)) * DIN + (t & 3) * 8;
  // frag-major dest (r9-verified bijective unit map)
  const int awoff = (((t >> 2) >> 4) * 64 + (t & 3) * 16 + ((t >> 2) & 15)) * 16;

  f32x4 acc[3][4][2];
#pragma unroll
  for (int g = 0; g < 3; ++g)
#pragma unroll
    for (int m = 0; m < 4; ++m)
#pragma unroll
      for (int n = 0; n < 2; ++n) acc[g][m][n] = (f32x4){0.f, 0.f, 0.f, 0.f};

  bf16x8 afr[4], bE[6], bO[6];
  float4 xE0, xE1, xO0, xO1;

#define LOADB(dst, kk) { \
  const unsigned short* _pb = pB + (size_t)(kk) * 12288; \
  _Pragma("unroll") for (int i = 0; i < 6; ++i) \
    dst[i] = *(const bf16x8*)(_pb + i * 512); }

#define READS(AB) { \
  _Pragma("unroll") for (int m = 0; m < 4; ++m) \
    afr[m] = *(const bf16x8*)(smem_ + (AB) * 4096 + (m * 64 + lane) * 16); }

#define MFMAP(BF) { \
  __builtin_amdgcn_s_setprio(1); \
  _Pragma("unroll") for (int g = 0; g < 3; ++g) \
  _Pragma("unroll") for (int m = 0; m < 4; ++m) { \
    acc[g][m][0] = __builtin_amdgcn_mfma_f32_16x16x32_bf16(afr[m], BF[g],     acc[g][m][0], 0, 0, 0); \
    acc[g][m][1] = __builtin_amdgcn_mfma_f32_16x16x32_bf16(afr[m], BF[3 + g], acc[g][m][1], 0, 0, 0); \
  } \
  __builtin_amdgcn_s_setprio(0); }

// step KK: compute from Abuf[AB] + CUR regs; prefetch B(KK+1)->NXT;
// load x(KK+2)->LD regs; write A(KK+1) from WR regs (loaded last step).
#define STEP(AB, CUR, NXT, KK, WR0, WR1, LD0, LD1) { \
  READS(AB); \
  { const int _kb = ((KK) + 1 < 31) ? (KK) + 1 : 31; LOADB(NXT, _kb); } \
  { const int _kx = ((KK) + 2 < 31) ? (KK) + 2 : 31; \
    const float* _px = pX + _kx * 32; \
    LD0 = *(const float4*)_px; LD1 = *(const float4*)(_px + 4); } \
  MFMAP(CUR); \
  *(bf16x8*)(smem_ + (((AB) ^ 1) * 4096) + awoff) = pack8(WR0, WR1); \
  WAITLGKM; \
  BARRIER; }

  // ---- prologue ----
  xE0 = *(const float4*)pX; xE1 = *(const float4*)(pX + 4);   // x(0)
  *(bf16x8*)(smem_ + awoff) = pack8(xE0, xE1);                // A(0) -> Abuf0
  LOADB(bE, 0);
  { const float* _px = pX + 32; xO0 = *(const float4*)_px; xO1 = *(const float4*)(_px + 4); }  // x(1)
  WAITLGKM;
  BARRIER;

  // ---- steps 0..31 (16 even/odd pairs; prefetch indices clamped at tail) ----
#pragma unroll 1
  for (int i = 0; i < 16; ++i) {
    const int k = i * 2;
    STEP(0, bE, bO, k,     xO0, xO1, xE0, xE1);   // write A(k+1) from xO; load x(k+2)->xE
    STEP(1, bO, bE, k + 1, xE0, xE1, xO0, xO1);   // write A(k+2) from xE; load x(k+3)->xO
  }
#undef STEP
#undef MFMAP
#undef READS
#undef LOADB

  // ---- epilogue (r5-r9-verified): p = (q*k)[c^1]*v[c]; fold rows; atomicAdd ----
  float pd0 = 0.f, pd1 = 0.f;
#pragma unroll
  for (int m = 0; m < 4; ++m)
#pragma unroll
    for (int r = 0; r < 4; ++r) {
      float qk0 = acc[0][m][0][r] * acc[1][m][0][r];
      float qk1 = acc[0][m][1][r] * acc[1][m][1][r];
      pd0 += __shfl_xor(qk0, 1, 64) * acc[2][m][0][r];
      pd1 += __shfl_xor(qk1, 1, 64) * acc[2][m][1][r];
    }
  pd0 += __shfl_xor(pd0, 16, 64); pd0 += __shfl_xor(pd0, 32, 64);
  pd1 += __shfl_xor(pd1, 16, 64); pd1 += __shfl_xor(pd1, 32, 64);

  // d = (ct*128 + w*32 + n*16 + (lane&15)) % 64 ; h-block = r0>>9 = rt>>3
  if (lane < 16) {
    float* dst = &outacc[((rt >> 3) << 6) + (w & 1) * 32 + lane];
    atomicAdd(dst, pd0);
    atomicAdd(dst + 16, pd1);
  }
}

// Finish: per-batch RMSNorm -> exact gelu -> @ Wout.T (verified r1-r9)
__global__ __launch_bounds__(256) void msr_finish(
    const float* __restrict__ outacc, const float* __restrict__ gamma,
    const float* __restrict__ Wout, float* __restrict__ y) {
  const int b = blockIdx.x;
  const int t = threadIdx.x;
  __shared__ float g[V_];
  __shared__ float wsum[4];

  float v0 = outacc[b * V_ + t] * CSCALE;
  float v1 = outacc[b * V_ + 256 + t] * CSCALE;
  float ss = v0 * v0 + v1 * v1;
#pragma unroll
  for (int o = 32; o > 0; o >>= 1) ss += __shfl_down(ss, o, 64);
  if ((t & 63) == 0) wsum[t >> 6] = ss;
  __syncthreads();
  float tot = wsum[0] + wsum[1] + wsum[2] + wsum[3];
  float rs = rsqrtf(tot * (1.0f / (float)V_) + EPSF);

  float r0v = v0 * rs * gamma[t];
  float r1v = v1 * rs * gamma[t + 256];
  g[t]       = 0.5f * r0v * (1.0f + erff(r0v * 0.70710678118654752f));
  g[t + 256] = 0.5f * r1v * (1.0f + erff(r1v * 0.70710678118654752f));
  __syncthreads();

  if (t < FOUT) {
    const float* wr = Wout + (size_t)t * V_;
    float acc = 0.f;
#pragma unroll 4
    for (int c = 0; c < V_; c += 4) {
      float4 w4 = *(const float4*)(wr + c);
      acc += g[c] * w4.x + g[c + 1] * w4.y + g[c + 2] * w4.z + g[c + 3] * w4.w;
    }
    y[b * FOUT + t] = acc;
  }
}

extern "C" void kernel_launch(void* const* d_in, const int* in_sizes, int n_in,
                              void* d_out, int out_size, void* d_ws, size_t ws_size,
                              hipStream_t stream) {
  const float* x     = (const float*)d_in[0];
  const float* Wq    = (const float*)d_in[1];
  const float* Wk    = (const float*)d_in[2];
  const float* Wv    = (const float*)d_in[3];
  const float* Wout  = (const float*)d_in[4];
  const float* gamma = (const float*)d_in[5];

  float* outacc = (float*)d_ws;                                  // 32 KB
  unsigned short* Wt = (unsigned short*)((char*)d_ws + 32768);   // 3 MB bf16 weights
  float* y = (float*)d_out;

  msr_convw<<<768, 256, 0, stream>>>(Wq, Wk, Wv, Wt);
  hipMemsetAsync(outacc, 0, B_ * V_ * sizeof(float), stream);
  msr_main<<<4096, 256, 0, stream>>>(x, Wt, outacc);
  msr_finish<<<B_, 256, 0, stream>>>(outacc, gamma, Wout, y);
}